// Round 6
// baseline (114.302 us; speedup 1.0000x reference)
//
#include <hip/hip_runtime.h>
#include <stdint.h>

#define B_  4
#define T_  2048
#define C_  1024
#define D_  64

typedef float  f32x4  __attribute__((ext_vector_type(4)));
typedef float  f32x16 __attribute__((ext_vector_type(16)));
typedef short  s16x8  __attribute__((ext_vector_type(8)));

// softmax scale folded into Q-side weights/bias: 1/sqrt(64) * log2(e)
#define QSCALE 0.18033688011112042f

static __device__ __forceinline__ uint32_t f2bf(float f) {
  uint32_t u = __builtin_bit_cast(uint32_t, f);
  u += 0x7FFFu + ((u >> 16) & 1u);   // round-to-nearest-even
  return u >> 16;
}
static __device__ __forceinline__ uint32_t pack2bf(float a, float b) {
  return f2bf(a) | (f2bf(b) << 16);
}

// ---------------------------------------------------------------------------
// Kernel 1: pack W into MFMA-A-fragment order (verified R3-R5).
// ---------------------------------------------------------------------------
__global__ __launch_bounds__(256) void wconv_kernel(
    const float* __restrict__ Wq, const float* __restrict__ bq,
    const float* __restrict__ Wk, const float* __restrict__ bk,
    const float* __restrict__ Wv, const float* __restrict__ bv,
    uint16_t* __restrict__ Wp, float* __restrict__ biascat) {
  const int g = blockIdx.x * 256 + threadIdx.x;  // 0..24575
  const int s32   = g / 768;
  const int rem   = g - s32 * 768;
  const int ntile = rem >> 6;
  const int l     = rem & 63;
  const int mrow  = l & 15, u = l >> 4;
  const int n     = ntile * 16 + mrow;
  const int mat   = n >> 6, col = n & 63;
  const float* W  = (mat == 0) ? Wq : ((mat == 1) ? Wk : Wv);
  const float  s  = (mat == 0) ? QSCALE : 1.0f;
  const int c0    = s32 * 32 + u * 8;
  float v[8];
#pragma unroll
  for (int j = 0; j < 8; ++j) v[j] = W[(size_t)(c0 + j) * D_ + col] * s;
  uint4 st;
  st.x = pack2bf(v[0], v[1]);
  st.y = pack2bf(v[2], v[3]);
  st.z = pack2bf(v[4], v[5]);
  st.w = pack2bf(v[6], v[7]);
  *reinterpret_cast<uint4*>(Wp + (size_t)g * 8) = st;
  if (g < 192) {
    float bb;
    if (g < 64)       bb = bq[g] * QSCALE;
    else if (g < 128) bb = bk[g - 64];
    else              bb = bv[g - 128];
    biascat[g] = bb;
  }
}

// ---------------------------------------------------------------------------
// Kernel 2: QKV projection. Depth-2 software pipeline: slab s+3 issued while
// computing slab s (2 reg buffers + 2 LDS buffers, 1 barrier/slab) -> ~1000
// cycles of HBM latency coverage. MFMA mapping verified R3-R5.
// ---------------------------------------------------------------------------
__global__ __launch_bounds__(256) void proj_kernel(
    const float* __restrict__ x, const uint16_t* __restrict__ Wp,
    const float* __restrict__ biascat,
    uint16_t* __restrict__ Qbf, uint16_t* __restrict__ Kbf,
    uint16_t* __restrict__ Vtile) {
  __shared__ __align__(16) uint16_t xt[2][16 * 132];    // 8448 B
  __shared__ __align__(16) uint16_t tbuf[4][16 * 28];   // 3584 B
  const int tid  = threadIdx.x;
  const int wave = tid >> 6;
  const int lane = tid & 63;
  const int mrow = lane & 15;
  const int u    = lane >> 4;
  const int m0   = blockIdx.x * 16;
  const int srow = tid >> 4, scol = tid & 15;

  const float* xg = x + (size_t)(m0 + srow) * C_ + scol * 4;

  f32x4 acc[3];
#pragma unroll
  for (int i = 0; i < 3; ++i)
#pragma unroll
    for (int r = 0; r < 4; ++r) acc[i][r] = 0.f;

  // prologue: slab0 -> LDS[0]; issue slab1 -> rb[0], slab2 -> rb[1]
  float4 rb[2][2];
  {
    float4 a0 = *reinterpret_cast<const float4*>(xg);
    float4 a1 = *reinterpret_cast<const float4*>(xg + 64);
    uint2 w0, w1;
    w0.x = pack2bf(a0.x, a0.y);  w0.y = pack2bf(a0.z, a0.w);
    w1.x = pack2bf(a1.x, a1.y);  w1.y = pack2bf(a1.z, a1.w);
    *reinterpret_cast<uint2*>(&xt[0][srow * 132 + scol * 4])      = w0;
    *reinterpret_cast<uint2*>(&xt[0][srow * 132 + scol * 4 + 64]) = w1;
  }
  rb[0][0] = *reinterpret_cast<const float4*>(xg + 128);
  rb[0][1] = *reinterpret_cast<const float4*>(xg + 192);
  rb[1][0] = *reinterpret_cast<const float4*>(xg + 256);
  rb[1][1] = *reinterpret_cast<const float4*>(xg + 320);
  __syncthreads();

  for (int s = 0; s < 8; ++s) {
    const int cur = s & 1;
#pragma unroll
    for (int step = 0; step < 4; ++step) {
      const int s32 = s * 4 + step;
      s16x8 bf = *reinterpret_cast<const s16x8*>(
          &xt[cur][mrow * 132 + step * 32 + u * 8]);
      const uint16_t* wb = Wp + ((size_t)(s32 * 12 + wave * 3) * 64 + lane) * 8;
      s16x8 a0 = *reinterpret_cast<const s16x8*>(wb);
      s16x8 a1 = *reinterpret_cast<const s16x8*>(wb + 64 * 8);
      s16x8 a2 = *reinterpret_cast<const s16x8*>(wb + 128 * 8);
      acc[0] = __builtin_amdgcn_mfma_f32_16x16x32_bf16(a0, bf, acc[0], 0, 0, 0);
      acc[1] = __builtin_amdgcn_mfma_f32_16x16x32_bf16(a1, bf, acc[1], 0, 0, 0);
      acc[2] = __builtin_amdgcn_mfma_f32_16x16x32_bf16(a2, bf, acc[2], 0, 0, 0);
    }
    if (s < 7) {
      // write slab s+1 (loaded 2 iterations ago) to the other LDS buffer
      uint2 w0, w1;
      w0.x = pack2bf(rb[cur][0].x, rb[cur][0].y);
      w0.y = pack2bf(rb[cur][0].z, rb[cur][0].w);
      w1.x = pack2bf(rb[cur][1].x, rb[cur][1].y);
      w1.y = pack2bf(rb[cur][1].z, rb[cur][1].w);
      *reinterpret_cast<uint2*>(&xt[cur ^ 1][srow * 132 + scol * 4])      = w0;
      *reinterpret_cast<uint2*>(&xt[cur ^ 1][srow * 132 + scol * 4 + 64]) = w1;
      if (s + 3 < 8) {  // issue slab s+3 into the just-freed reg buffer
        rb[cur][0] = *reinterpret_cast<const float4*>(xg + (s + 3) * 128);
        rb[cur][1] = *reinterpret_cast<const float4*>(xg + (s + 3) * 128 + 64);
      }
      __syncthreads();
    }
  }

  const int bb  = m0 >> 11;        // batch
  const int mm  = m0 & (T_ - 1);   // t offset within batch
#pragma unroll
  for (int nt = 0; nt < 3; ++nt) {
    const int nb = wave * 48 + nt * 16;
    uint16_t vals[4];
#pragma unroll
    for (int r = 0; r < 4; ++r)
      vals[r] = (uint16_t)f2bf(acc[nt][r] + biascat[nb + u * 4 + r]);
    if (nb >= 128) {
      // V -> tiled layout [b][t32][d][32t]
      const int tl   = mm >> 5;
      const int toff = (mm & 31) + mrow;
#pragma unroll
      for (int r = 0; r < 4; ++r) {
        int vrow = nb - 128 + u * 4 + r;
        Vtile[(((size_t)bb * 64 + tl) * 64 + vrow) * 32 + toff] = vals[r];
      }
    } else {
      // Q/K: per-wave LDS transpose, then 8B stores
#pragma unroll
      for (int r = 0; r < 4; ++r)
        tbuf[wave][mrow * 28 + u * 4 + r] = vals[r];
      const int row = lane >> 2, qtr = lane & 3;
      uint2 v = *reinterpret_cast<const uint2*>(&tbuf[wave][row * 28 + qtr * 4]);
      uint16_t* dst = (nb < 64) ? (Qbf + nb) : (Kbf + (nb - 64));
      *reinterpret_cast<uint2*>(dst + (size_t)(m0 + row) * D_ + qtr * 4) = v;
    }
  }
}

// ---------------------------------------------------------------------------
// Kernel 3: attention (R5-verified structure), chunk halved to 8 k-tiles:
// 288 jobs/batch, 1152 blocks, <=2 serial k-steps per wave. Zero LDS in the
// k-loop; P transform via shfl_xor lane-pair exchange (verified R5).
// slot(dm,r,hi,ql) = dm*1024 + r*64 + hi*32 + ql.
// ---------------------------------------------------------------------------
__global__ __launch_bounds__(256) void attn_kernel(
    const uint16_t* __restrict__ Qbf, const uint16_t* __restrict__ Kbf,
    const uint16_t* __restrict__ Vtile, float* __restrict__ partial,
    float* __restrict__ lpart) {
  __shared__ float wpart[4 * 2048];   // 32768 B
  __shared__ float lw[128];           // 512 B

  const int tid  = threadIdx.x;
  const int wave = tid >> 6;
  const int lane = tid & 63;
  const int ql   = lane & 31;
  const int hi   = lane >> 5;

  const int blk = blockIdx.x;          // 1152 = 8 swizzle x 144
  const int b   = (blk & 7) >> 1;
  const int j   = 2 * (blk >> 3) + (blk & 1);   // 0..287

  // decode j -> (qt, chunk of 8): qt = 8a + r has a+1 chunks;
  // group a occupies [4a(a+1), 4(a+1)(a+2))
  int a_ = 0;
  while (4 * (a_ + 1) * (a_ + 2) <= j) ++a_;
  const int off = j - 4 * a_ * (a_ + 1);
  const int r_  = off / (a_ + 1);
  const int ch  = off - r_ * (a_ + 1);
  const int qt  = 8 * a_ + r_;
  const int c8  = ch * 8;
  const int qb  = qt * 32;
  const int tmax = min(c8 + 7, qt);
  const int pj  = b * 288 + j;

  const uint16_t* Qb = Qbf + (size_t)b * T_ * D_;
  const uint16_t* Kb = Kbf + (size_t)b * T_ * D_;

  // Q fragments direct from global (16B/lane, L2-served)
  const uint16_t* qg = Qb + (size_t)(qb + ql) * D_ + hi * 8;
  s16x8 qf[4];
#pragma unroll
  for (int c = 0; c < 4; ++c)
    qf[c] = *reinterpret_cast<const s16x8*>(qg + c * 16);

  f32x16 aco[2];
#pragma unroll
  for (int i = 0; i < 2; ++i)
#pragma unroll
    for (int r = 0; r < 16; ++r) aco[i][r] = 0.f;
  float lacc = 0.f;

  auto load_tile = [&](int t, s16x8* kf, s16x8* vf) {
    const uint16_t* kg = Kb + (size_t)(t * 32 + ql) * D_ + hi * 8;
#pragma unroll
    for (int c = 0; c < 4; ++c)
      kf[c] = *reinterpret_cast<const s16x8*>(kg + c * 16);
    const uint16_t* vg = Vtile + ((size_t)(b * 64 + t) * 64 + ql) * 32 + hi * 8;
    vf[0] = *reinterpret_cast<const s16x8*>(vg);              // dm0 kc0
    vf[1] = *reinterpret_cast<const s16x8*>(vg + 16);         // dm0 kc1
    vf[2] = *reinterpret_cast<const s16x8*>(vg + 1024);       // dm1 kc0
    vf[3] = *reinterpret_cast<const s16x8*>(vg + 1024 + 16);  // dm1 kc1
  };

  auto compute = [&](int t, const s16x8* kf, const s16x8* vf) {
    f32x16 sacc;
#pragma unroll
    for (int r = 0; r < 16; ++r) sacc[r] = 0.f;
#pragma unroll
    for (int c = 0; c < 4; ++c)
      sacc = __builtin_amdgcn_mfma_f32_32x32x16_bf16(kf[c], qf[c], sacc, 0, 0, 0);
    if (t == qt) {  // diagonal tile: causal mask
#pragma unroll
      for (int r = 0; r < 16; ++r) {
        const int koff = (r & 3) + 8 * (r >> 2) + 4 * hi;
        sacc[r] = (koff > ql) ? -1e30f : sacc[r];
      }
    }
    float p[16];
#pragma unroll
    for (int r = 0; r < 16; ++r) p[r] = __builtin_amdgcn_exp2f(sacc[r]);
    float s01 = (p[0] + p[1]) + (p[2] + p[3]);
    float s23 = (p[4] + p[5]) + (p[6] + p[7]);
    float s45 = (p[8] + p[9]) + (p[10] + p[11]);
    float s67 = (p[12] + p[13]) + (p[14] + p[15]);
    lacc += (s01 + s23) + (s45 + s67);

    // P -> B-frag via lane-pair exchange (ql <-> ql+32), verified R5
    uint32_t A0 = pack2bf(p[0], p[1]),  A1 = pack2bf(p[2], p[3]);
    uint32_t B0 = pack2bf(p[4], p[5]),  B1 = pack2bf(p[6], p[7]);
    uint32_t C0 = pack2bf(p[8], p[9]),  C1 = pack2bf(p[10], p[11]);
    uint32_t D0 = pack2bf(p[12], p[13]), D1 = pack2bf(p[14], p[15]);
    uint32_t r0 = (uint32_t)__shfl_xor((int)(hi ? A0 : B0), 32, 64);
    uint32_t r1 = (uint32_t)__shfl_xor((int)(hi ? A1 : B1), 32, 64);
    uint32_t r2 = (uint32_t)__shfl_xor((int)(hi ? C0 : D0), 32, 64);
    uint32_t r3 = (uint32_t)__shfl_xor((int)(hi ? C1 : D1), 32, 64);
    union { uint32_t u[4]; s16x8 v; } pf0, pf1;
    pf0.u[0] = hi ? r0 : A0;  pf0.u[1] = hi ? r1 : A1;
    pf0.u[2] = hi ? B0 : r0;  pf0.u[3] = hi ? B1 : r1;
    pf1.u[0] = hi ? r2 : C0;  pf1.u[1] = hi ? r3 : C1;
    pf1.u[2] = hi ? D0 : r2;  pf1.u[3] = hi ? D1 : r3;
    aco[0] = __builtin_amdgcn_mfma_f32_32x32x16_bf16(vf[0], pf0.v, aco[0], 0, 0, 0);
    aco[1] = __builtin_amdgcn_mfma_f32_32x32x16_bf16(vf[2], pf0.v, aco[1], 0, 0, 0);
    aco[0] = __builtin_amdgcn_mfma_f32_32x32x16_bf16(vf[1], pf1.v, aco[0], 0, 0, 0);
    aco[1] = __builtin_amdgcn_mfma_f32_32x32x16_bf16(vf[3], pf1.v, aco[1], 0, 0, 0);
  };

  // register-double-buffered k-loop (<=2 tiles per wave)
  {
    int t = c8 + wave;
    if (t <= tmax) {
      s16x8 kfA[4], vfA[4], kfB[4], vfB[4];
      load_tile(t, kfA, vfA);
      while (true) {
        int tn = t + 4;
        if (tn <= tmax) load_tile(tn, kfB, vfB);
        compute(t, kfA, vfA);
        if (tn > tmax) break;
        t = tn; tn = t + 4;
        if (tn <= tmax) load_tile(tn, kfA, vfA);
        compute(t, kfB, vfB);
        if (tn > tmax) break;
        t = tn;
      }
    }
  }

  lacc += __shfl_xor(lacc, 32, 64);

  // wave-private dump + merge (verified R4/R5)
#pragma unroll
  for (int dm = 0; dm < 2; ++dm)
#pragma unroll
    for (int r = 0; r < 16; ++r)
      wpart[wave * 2048 + dm * 1024 + r * 64 + hi * 32 + ql] = aco[dm][r];
  if (hi == 0) lw[wave * 32 + ql] = lacc;
  __syncthreads();

  {
    const int base = tid * 8;
    float4 s0 = {0.f, 0.f, 0.f, 0.f}, s1 = {0.f, 0.f, 0.f, 0.f};
#pragma unroll
    for (int w = 0; w < 4; ++w) {
      const float* p = wpart + w * 2048 + base;
      float4 a = *reinterpret_cast<const float4*>(p);
      float4 c = *reinterpret_cast<const float4*>(p + 4);
      s0.x += a.x; s0.y += a.y; s0.z += a.z; s0.w += a.w;
      s1.x += c.x; s1.y += c.y; s1.z += c.z; s1.w += c.w;
    }
    float* pp = partial + (size_t)pj * 2048 + base;
    *reinterpret_cast<float4*>(pp)     = s0;
    *reinterpret_cast<float4*>(pp + 4) = s1;
    if (tid < 32) {
      float ls = (lw[tid] + lw[32 + tid]) + (lw[64 + tid] + lw[96 + tid]);
      lpart[(size_t)pj * 32 + tid] = ls;
    }
  }
}

// ---------------------------------------------------------------------------
// Kernel 4: reduce chunk partials (slot space, <=8 per q-tile), decode,
// normalize, write out fp32 coalesced via LDS transpose.
// ---------------------------------------------------------------------------
__global__ __launch_bounds__(256) void reduce_kernel(
    const float* __restrict__ partial, const float* __restrict__ lpart,
    float* __restrict__ out) {
  __shared__ float trans[64 * 33];
  __shared__ float lbuf[32];
  const int blk = blockIdx.x;          // 256 = 4 b x 64 qt
  const int b   = blk >> 6;
  const int qt  = blk & 63;
  const int a_  = qt >> 3;
  const int nch = a_ + 1;
  const int pjb = b * 288 + 4 * a_ * (a_ + 1) + (qt & 7) * (a_ + 1);
  const int t   = threadIdx.x;

  if (t < 32) {
    float s = 0.f;
    for (int c = 0; c < nch; ++c) s += lpart[(size_t)(pjb + c) * 32 + t];
    lbuf[t] = 1.0f / s;
  }

  const int base = t * 8;
  float4 s0 = {0.f, 0.f, 0.f, 0.f}, s1 = {0.f, 0.f, 0.f, 0.f};
  for (int c = 0; c < nch; ++c) {
    const float* p = partial + (size_t)(pjb + c) * 2048 + base;
    float4 a = *reinterpret_cast<const float4*>(p);
    float4 d = *reinterpret_cast<const float4*>(p + 4);
    s0.x += a.x; s0.y += a.y; s0.z += a.z; s0.w += a.w;
    s1.x += d.x; s1.y += d.y; s1.z += d.z; s1.w += d.w;
  }
  const int dm = base >> 10, r = (base >> 6) & 15, hi = (base >> 5) & 1;
  const int ql0 = base & 31;
  const int d = dm * 32 + (r & 3) + 8 * (r >> 2) + 4 * hi;
  float* tr = &trans[d * 33 + ql0];
  tr[0] = s0.x; tr[1] = s0.y; tr[2] = s0.z; tr[3] = s0.w;
  tr[4] = s1.x; tr[5] = s1.y; tr[6] = s1.z; tr[7] = s1.w;
  __syncthreads();

  const int q  = t >> 3;
  const int dg = (t & 7) * 8;
  const float rinv = lbuf[q];
  float4 o0, o1;
  o0.x = trans[(dg + 0) * 33 + q] * rinv;
  o0.y = trans[(dg + 1) * 33 + q] * rinv;
  o0.z = trans[(dg + 2) * 33 + q] * rinv;
  o0.w = trans[(dg + 3) * 33 + q] * rinv;
  o1.x = trans[(dg + 4) * 33 + q] * rinv;
  o1.y = trans[(dg + 5) * 33 + q] * rinv;
  o1.z = trans[(dg + 6) * 33 + q] * rinv;
  o1.w = trans[(dg + 7) * 33 + q] * rinv;
  float* op = out + ((size_t)(b * T_ + qt * 32 + q)) * D_ + dg;
  *reinterpret_cast<float4*>(op)     = o0;
  *reinterpret_cast<float4*>(op + 4) = o1;
}

// ---------------------------------------------------------------------------
extern "C" void kernel_launch(void* const* d_in, const int* in_sizes, int n_in,
                              void* d_out, int out_size, void* d_ws, size_t ws_size,
                              hipStream_t stream) {
  (void)in_sizes; (void)n_in; (void)out_size; (void)ws_size;
  const float* x  = (const float*)d_in[0];
  const float* Wq = (const float*)d_in[1];
  const float* bq = (const float*)d_in[2];
  const float* Wk = (const float*)d_in[3];
  const float* bk = (const float*)d_in[4];
  const float* Wv = (const float*)d_in[5];
  const float* bv = (const float*)d_in[6];
  float* out = (float*)d_out;

  char* ws = (char*)d_ws;
  uint16_t* Wp      = (uint16_t*)(ws);                 // 393,216 B
  float*    biascat = (float*)(ws + 393216);           // 1,024 B (768 used)
  uint16_t* Qbf     = (uint16_t*)(ws + 394240);        // 1,048,576 B
  uint16_t* Kbf     = (uint16_t*)(ws + 1442816);       // 1,048,576 B
  uint16_t* Vtile   = (uint16_t*)(ws + 2491392);       // 1,048,576 B
  float*    partial = (float*)(ws + 3539968);          // 9,437,184 B
  float*    lpart   = (float*)(ws + 12977152);         // 147,456 B

  hipLaunchKernelGGL(wconv_kernel, dim3(96), dim3(256), 0, stream,
                     Wq, bq, Wk, bk, Wv, bv, Wp, biascat);
  hipLaunchKernelGGL(proj_kernel, dim3(512), dim3(256), 0, stream,
                     x, Wp, biascat, Qbf, Kbf, Vtile);
  hipLaunchKernelGGL(attn_kernel, dim3(1152), dim3(256), 0, stream,
                     Qbf, Kbf, Vtile, partial, lpart);
  hipLaunchKernelGGL(reduce_kernel, dim3(256), dim3(256), 0, stream,
                     partial, lpart, out);
}

// Round 7
// 105.687 us; speedup vs baseline: 1.0815x; 1.0815x over previous
//
#include <hip/hip_runtime.h>
#include <stdint.h>

#define B_  4
#define T_  2048
#define C_  1024
#define D_  64

typedef float  f32x4  __attribute__((ext_vector_type(4)));
typedef float  f32x16 __attribute__((ext_vector_type(16)));
typedef short  s16x8  __attribute__((ext_vector_type(8)));

// softmax scale folded into Q-side weights/bias: 1/sqrt(64) * log2(e)
#define QSCALE 0.18033688011112042f

static __device__ __forceinline__ uint32_t f2bf(float f) {
  uint32_t u = __builtin_bit_cast(uint32_t, f);
  u += 0x7FFFu + ((u >> 16) & 1u);   // round-to-nearest-even
  return u >> 16;
}
static __device__ __forceinline__ uint32_t pack2bf(float a, float b) {
  return f2bf(a) | (f2bf(b) << 16);
}

// ---------------------------------------------------------------------------
// Kernel 1: pack W into MFMA-A-fragment order (verified R3-R6).
// ---------------------------------------------------------------------------
__global__ __launch_bounds__(256) void wconv_kernel(
    const float* __restrict__ Wq, const float* __restrict__ bq,
    const float* __restrict__ Wk, const float* __restrict__ bk,
    const float* __restrict__ Wv, const float* __restrict__ bv,
    uint16_t* __restrict__ Wp, float* __restrict__ biascat) {
  const int g = blockIdx.x * 256 + threadIdx.x;  // 0..24575
  const int s32   = g / 768;
  const int rem   = g - s32 * 768;
  const int ntile = rem >> 6;
  const int l     = rem & 63;
  const int mrow  = l & 15, u = l >> 4;
  const int n     = ntile * 16 + mrow;
  const int mat   = n >> 6, col = n & 63;
  const float* W  = (mat == 0) ? Wq : ((mat == 1) ? Wk : Wv);
  const float  s  = (mat == 0) ? QSCALE : 1.0f;
  const int c0    = s32 * 32 + u * 8;
  float v[8];
#pragma unroll
  for (int j = 0; j < 8; ++j) v[j] = W[(size_t)(c0 + j) * D_ + col] * s;
  uint4 st;
  st.x = pack2bf(v[0], v[1]);
  st.y = pack2bf(v[2], v[3]);
  st.z = pack2bf(v[4], v[5]);
  st.w = pack2bf(v[6], v[7]);
  *reinterpret_cast<uint4*>(Wp + (size_t)g * 8) = st;
  if (g < 192) {
    float bb;
    if (g < 64)       bb = bq[g] * QSCALE;
    else if (g < 128) bb = bk[g - 64];
    else              bb = bv[g - 128];
    biascat[g] = bb;
  }
}

// ---------------------------------------------------------------------------
// Kernel 2: QKV projection (R5-verified pipeline). Epilogue now stores Q/K/V
// in ATTN-FRAGMENT order so attn's loads are wave-contiguous 16B/lane:
//   Q/K: elem [m][e] -> tile(b*64 + (m&2047)>>5) + (e>>4)*512
//                       + (((e>>3)&1)*32 + (m&31))*8 + (e&7)
//   V:   elem V^T[d][tg] -> tile(b*64 + tg>>5) + ((d>>5)*2 + ((tg&31)>>4))*512
//                       + ((((tg&31)>>3)&1)*32 + (d&31))*8 + (tg&7)
// ---------------------------------------------------------------------------
__global__ __launch_bounds__(256) void proj_kernel(
    const float* __restrict__ x, const uint16_t* __restrict__ Wp,
    const float* __restrict__ biascat,
    uint16_t* __restrict__ Qfrag, uint16_t* __restrict__ Kfrag,
    uint16_t* __restrict__ Vfrag) {
  __shared__ __align__(16) uint16_t xt[2][16 * 132];    // 8448 B
  __shared__ __align__(16) uint16_t tbuf[4][16 * 28];   // 3584 B
  const int tid  = threadIdx.x;
  const int wave = tid >> 6;
  const int lane = tid & 63;
  const int mrow = lane & 15;
  const int u    = lane >> 4;
  const int m0   = blockIdx.x * 16;
  const int srow = tid >> 4, scol = tid & 15;

  const float* xg = x + (size_t)(m0 + srow) * C_ + scol * 4;

  f32x4 acc[3];
#pragma unroll
  for (int i = 0; i < 3; ++i)
#pragma unroll
    for (int r = 0; r < 4; ++r) acc[i][r] = 0.f;

  // slab 0: load + store to xt[0]
  float4 xv0 = *reinterpret_cast<const float4*>(xg);
  float4 xv1 = *reinterpret_cast<const float4*>(xg + 64);
  {
    uint2 w0, w1;
    w0.x = pack2bf(xv0.x, xv0.y);  w0.y = pack2bf(xv0.z, xv0.w);
    w1.x = pack2bf(xv1.x, xv1.y);  w1.y = pack2bf(xv1.z, xv1.w);
    *reinterpret_cast<uint2*>(&xt[0][srow * 132 + scol * 4])      = w0;
    *reinterpret_cast<uint2*>(&xt[0][srow * 132 + scol * 4 + 64]) = w1;
  }
  __syncthreads();

  for (int s = 0; s < 8; ++s) {
    const int cur = s & 1;
    if (s < 7) {  // prefetch next slab (overlaps the 12 MFMAs below)
      xv0 = *reinterpret_cast<const float4*>(xg + (s + 1) * 128);
      xv1 = *reinterpret_cast<const float4*>(xg + (s + 1) * 128 + 64);
    }
#pragma unroll
    for (int step = 0; step < 4; ++step) {
      const int s32 = s * 4 + step;
      s16x8 bf = *reinterpret_cast<const s16x8*>(
          &xt[cur][mrow * 132 + step * 32 + u * 8]);
      const uint16_t* wb = Wp + ((size_t)(s32 * 12 + wave * 3) * 64 + lane) * 8;
      s16x8 a0 = *reinterpret_cast<const s16x8*>(wb);
      s16x8 a1 = *reinterpret_cast<const s16x8*>(wb + 64 * 8);
      s16x8 a2 = *reinterpret_cast<const s16x8*>(wb + 128 * 8);
      acc[0] = __builtin_amdgcn_mfma_f32_16x16x32_bf16(a0, bf, acc[0], 0, 0, 0);
      acc[1] = __builtin_amdgcn_mfma_f32_16x16x32_bf16(a1, bf, acc[1], 0, 0, 0);
      acc[2] = __builtin_amdgcn_mfma_f32_16x16x32_bf16(a2, bf, acc[2], 0, 0, 0);
    }
    if (s < 7) {  // write next slab to the other buffer, single barrier
      uint2 w0, w1;
      w0.x = pack2bf(xv0.x, xv0.y);  w0.y = pack2bf(xv0.z, xv0.w);
      w1.x = pack2bf(xv1.x, xv1.y);  w1.y = pack2bf(xv1.z, xv1.w);
      *reinterpret_cast<uint2*>(&xt[cur ^ 1][srow * 132 + scol * 4])      = w0;
      *reinterpret_cast<uint2*>(&xt[cur ^ 1][srow * 132 + scol * 4 + 64]) = w1;
      __syncthreads();
    }
  }

  const int bb  = m0 >> 11;        // batch
  const int mm  = m0 & (T_ - 1);   // t offset within batch
#pragma unroll
  for (int nt = 0; nt < 3; ++nt) {
    const int nb = wave * 48 + nt * 16;
    uint16_t vals[4];
#pragma unroll
    for (int r = 0; r < 4; ++r)
      vals[r] = (uint16_t)f2bf(acc[nt][r] + biascat[nb + u * 4 + r]);
    if (nb >= 128) {
      // V -> fragment-major: elem V^T[d][tg]
      const int tg  = mm + mrow;           // within-batch t index
      const int t   = tg >> 5, rem = tg & 31;
      const int kc  = rem >> 4, hi2 = (rem >> 3) & 1, jj = rem & 7;
      uint16_t* base = Vfrag + ((size_t)(bb * 64 + t)) * 2048;
#pragma unroll
      for (int r = 0; r < 4; ++r) {
        int d = nb - 128 + u * 4 + r;
        int i = (d >> 5) * 2 + kc;
        int l = hi2 * 32 + (d & 31);
        base[i * 512 + l * 8 + jj] = vals[r];
      }
    } else {
      // Q/K: per-wave LDS transpose, then 8B fragment-order stores
#pragma unroll
      for (int r = 0; r < 4; ++r)
        tbuf[wave][mrow * 28 + u * 4 + r] = vals[r];
      const int row = lane >> 2, qtr = lane & 3;
      uint2 v = *reinterpret_cast<const uint2*>(&tbuf[wave][row * 28 + qtr * 4]);
      const int m  = m0 + row;             // global q/k row
      const int e0 = (nb & 63) + qtr * 4;  // col within 64 (Q: nb, K: nb-64)
      const int t  = (m & 2047) >> 5;
      const int c  = e0 >> 4, hi2 = (e0 >> 3) & 1, j0 = e0 & 7;
      uint16_t* dst = (nb < 64) ? Qfrag : Kfrag;
      *reinterpret_cast<uint2*>(
          dst + ((size_t)(bb * 64 + t)) * 2048 + c * 512 +
          (hi2 * 32 + (m & 31)) * 8 + j0) = v;
    }
  }
}

// ---------------------------------------------------------------------------
// Kernel 3: attention (R5-verified structure, chunk=16/640 blocks). All
// Q/K/V loads are fragment-major: base + instr*512 + lane*8 -> 64 lanes x
// 16B contiguous (4 lines/instr, zero fragmentation). Zero LDS in k-loop;
// P transform via shfl_xor lane-pair exchange (verified R5/R6).
// slot(dm,r,hi,ql) = dm*1024 + r*64 + hi*32 + ql.
// ---------------------------------------------------------------------------
__global__ __launch_bounds__(256) void attn_kernel(
    const uint16_t* __restrict__ Qfrag, const uint16_t* __restrict__ Kfrag,
    const uint16_t* __restrict__ Vfrag, float* __restrict__ partial,
    float* __restrict__ lpart) {
  __shared__ float wpart[4 * 2048];   // 32768 B
  __shared__ float lw[128];           // 512 B

  const int tid  = threadIdx.x;
  const int wave = tid >> 6;
  const int lane = tid & 63;
  const int ql   = lane & 31;
  const int hi   = lane >> 5;

  const int blk = blockIdx.x;
  const int b   = (blk & 7) >> 1;
  const int j   = 2 * (blk >> 3) + (blk & 1);   // 0..159

  int a_ = 0;
  while (8 * (a_ + 1) * (a_ + 2) <= j) ++a_;
  const int off = j - 8 * a_ * (a_ + 1);
  const int r_  = off / (a_ + 1);
  const int ch  = off - r_ * (a_ + 1);
  const int qt  = 16 * a_ + r_;
  const int c16 = ch * 16;
  const int tmax = min(c16 + 15, qt);
  const int pj  = b * 160 + j;

  // Q fragments: coalesced 16B/lane
  s16x8 qf[4];
  {
    const uint16_t* qg = Qfrag + ((size_t)(b * 64 + qt)) * 2048 + lane * 8;
#pragma unroll
    for (int c = 0; c < 4; ++c)
      qf[c] = *reinterpret_cast<const s16x8*>(qg + c * 512);
  }

  f32x16 aco[2];
#pragma unroll
  for (int i = 0; i < 2; ++i)
#pragma unroll
    for (int r = 0; r < 16; ++r) aco[i][r] = 0.f;
  float lacc = 0.f;

  auto load_tile = [&](int t, s16x8* kf, s16x8* vf) {
    const uint16_t* kg = Kfrag + ((size_t)(b * 64 + t)) * 2048 + lane * 8;
#pragma unroll
    for (int c = 0; c < 4; ++c)
      kf[c] = *reinterpret_cast<const s16x8*>(kg + c * 512);
    const uint16_t* vg = Vfrag + ((size_t)(b * 64 + t)) * 2048 + lane * 8;
#pragma unroll
    for (int i = 0; i < 4; ++i)   // i = dm*2+kc
      vf[i] = *reinterpret_cast<const s16x8*>(vg + i * 512);
  };

  auto compute = [&](int t, const s16x8* kf, const s16x8* vf) {
    f32x16 sacc;
#pragma unroll
    for (int r = 0; r < 16; ++r) sacc[r] = 0.f;
#pragma unroll
    for (int c = 0; c < 4; ++c)
      sacc = __builtin_amdgcn_mfma_f32_32x32x16_bf16(kf[c], qf[c], sacc, 0, 0, 0);
    if (t == qt) {  // diagonal tile: causal mask
#pragma unroll
      for (int r = 0; r < 16; ++r) {
        const int koff = (r & 3) + 8 * (r >> 2) + 4 * hi;
        sacc[r] = (koff > ql) ? -1e30f : sacc[r];
      }
    }
    float p[16];
#pragma unroll
    for (int r = 0; r < 16; ++r) p[r] = __builtin_amdgcn_exp2f(sacc[r]);
    float s01 = (p[0] + p[1]) + (p[2] + p[3]);
    float s23 = (p[4] + p[5]) + (p[6] + p[7]);
    float s45 = (p[8] + p[9]) + (p[10] + p[11]);
    float s67 = (p[12] + p[13]) + (p[14] + p[15]);
    lacc += (s01 + s23) + (s45 + s67);

    // P -> B-frag via lane-pair exchange (ql <-> ql+32), verified R5/R6
    uint32_t A0 = pack2bf(p[0], p[1]),  A1 = pack2bf(p[2], p[3]);
    uint32_t B0 = pack2bf(p[4], p[5]),  B1 = pack2bf(p[6], p[7]);
    uint32_t C0 = pack2bf(p[8], p[9]),  C1 = pack2bf(p[10], p[11]);
    uint32_t D0 = pack2bf(p[12], p[13]), D1 = pack2bf(p[14], p[15]);
    uint32_t r0 = (uint32_t)__shfl_xor((int)(hi ? A0 : B0), 32, 64);
    uint32_t r1 = (uint32_t)__shfl_xor((int)(hi ? A1 : B1), 32, 64);
    uint32_t r2 = (uint32_t)__shfl_xor((int)(hi ? C0 : D0), 32, 64);
    uint32_t r3 = (uint32_t)__shfl_xor((int)(hi ? C1 : D1), 32, 64);
    union { uint32_t u[4]; s16x8 v; } pf0, pf1;
    pf0.u[0] = hi ? r0 : A0;  pf0.u[1] = hi ? r1 : A1;
    pf0.u[2] = hi ? B0 : r0;  pf0.u[3] = hi ? B1 : r1;
    pf1.u[0] = hi ? r2 : C0;  pf1.u[1] = hi ? r3 : C1;
    pf1.u[2] = hi ? D0 : r2;  pf1.u[3] = hi ? D1 : r3;
    aco[0] = __builtin_amdgcn_mfma_f32_32x32x16_bf16(vf[0], pf0.v, aco[0], 0, 0, 0);
    aco[1] = __builtin_amdgcn_mfma_f32_32x32x16_bf16(vf[2], pf0.v, aco[1], 0, 0, 0);
    aco[0] = __builtin_amdgcn_mfma_f32_32x32x16_bf16(vf[1], pf1.v, aco[0], 0, 0, 0);
    aco[1] = __builtin_amdgcn_mfma_f32_32x32x16_bf16(vf[3], pf1.v, aco[1], 0, 0, 0);
  };

  // register-double-buffered k-loop (<=4 tiles per wave)
  {
    int t = c16 + wave;
    if (t <= tmax) {
      s16x8 kfA[4], vfA[4], kfB[4], vfB[4];
      load_tile(t, kfA, vfA);
      while (true) {
        int tn = t + 4;
        if (tn <= tmax) load_tile(tn, kfB, vfB);
        compute(t, kfA, vfA);
        if (tn > tmax) break;
        t = tn; tn = t + 4;
        if (tn <= tmax) load_tile(tn, kfA, vfA);
        compute(t, kfB, vfB);
        if (tn > tmax) break;
        t = tn;
      }
    }
  }

  lacc += __shfl_xor(lacc, 32, 64);

  // wave-private dump + merge (verified R4/R5)
#pragma unroll
  for (int dm = 0; dm < 2; ++dm)
#pragma unroll
    for (int r = 0; r < 16; ++r)
      wpart[wave * 2048 + dm * 1024 + r * 64 + hi * 32 + ql] = aco[dm][r];
  if (hi == 0) lw[wave * 32 + ql] = lacc;
  __syncthreads();

  {
    const int base = tid * 8;
    float4 s0 = {0.f, 0.f, 0.f, 0.f}, s1 = {0.f, 0.f, 0.f, 0.f};
#pragma unroll
    for (int w = 0; w < 4; ++w) {
      const float* p = wpart + w * 2048 + base;
      float4 a = *reinterpret_cast<const float4*>(p);
      float4 c = *reinterpret_cast<const float4*>(p + 4);
      s0.x += a.x; s0.y += a.y; s0.z += a.z; s0.w += a.w;
      s1.x += c.x; s1.y += c.y; s1.z += c.z; s1.w += c.w;
    }
    float* pp = partial + (size_t)pj * 2048 + base;
    *reinterpret_cast<float4*>(pp)     = s0;
    *reinterpret_cast<float4*>(pp + 4) = s1;
    if (tid < 32) {
      float ls = (lw[tid] + lw[32 + tid]) + (lw[64 + tid] + lw[96 + tid]);
      lpart[(size_t)pj * 32 + tid] = ls;
    }
  }
}

// ---------------------------------------------------------------------------
// Kernel 4: reduce chunk partials (slot space, <=4 per q-tile), decode,
// normalize, write out fp32 coalesced via LDS transpose. (R5-verified.)
// ---------------------------------------------------------------------------
__global__ __launch_bounds__(256) void reduce_kernel(
    const float* __restrict__ partial, const float* __restrict__ lpart,
    float* __restrict__ out) {
  __shared__ float trans[64 * 33];
  __shared__ float lbuf[32];
  const int blk = blockIdx.x;          // 256 = 4 b x 64 qt
  const int b   = blk >> 6;
  const int qt  = blk & 63;
  const int a_  = qt >> 4;
  const int nch = a_ + 1;
  const int pjb = b * 160 + 8 * a_ * (a_ + 1) + (qt & 15) * (a_ + 1);
  const int t   = threadIdx.x;

  if (t < 32) {
    float s = 0.f;
    for (int c = 0; c < nch; ++c) s += lpart[(size_t)(pjb + c) * 32 + t];
    lbuf[t] = 1.0f / s;
  }

  const int base = t * 8;
  float4 s0 = {0.f, 0.f, 0.f, 0.f}, s1 = {0.f, 0.f, 0.f, 0.f};
  for (int c = 0; c < nch; ++c) {
    const float* p = partial + (size_t)(pjb + c) * 2048 + base;
    float4 a = *reinterpret_cast<const float4*>(p);
    float4 d = *reinterpret_cast<const float4*>(p + 4);
    s0.x += a.x; s0.y += a.y; s0.z += a.z; s0.w += a.w;
    s1.x += d.x; s1.y += d.y; s1.z += d.z; s1.w += d.w;
  }
  const int dm = base >> 10, r = (base >> 6) & 15, hi = (base >> 5) & 1;
  const int ql0 = base & 31;
  const int d = dm * 32 + (r & 3) + 8 * (r >> 2) + 4 * hi;
  float* tr = &trans[d * 33 + ql0];
  tr[0] = s0.x; tr[1] = s0.y; tr[2] = s0.z; tr[3] = s0.w;
  tr[4] = s1.x; tr[5] = s1.y; tr[6] = s1.z; tr[7] = s1.w;
  __syncthreads();

  const int q  = t >> 3;
  const int dg = (t & 7) * 8;
  const float rinv = lbuf[q];
  float4 o0, o1;
  o0.x = trans[(dg + 0) * 33 + q] * rinv;
  o0.y = trans[(dg + 1) * 33 + q] * rinv;
  o0.z = trans[(dg + 2) * 33 + q] * rinv;
  o0.w = trans[(dg + 3) * 33 + q] * rinv;
  o1.x = trans[(dg + 4) * 33 + q] * rinv;
  o1.y = trans[(dg + 5) * 33 + q] * rinv;
  o1.z = trans[(dg + 6) * 33 + q] * rinv;
  o1.w = trans[(dg + 7) * 33 + q] * rinv;
  float* op = out + ((size_t)(b * T_ + qt * 32 + q)) * D_ + dg;
  *reinterpret_cast<float4*>(op)     = o0;
  *reinterpret_cast<float4*>(op + 4) = o1;
}

// ---------------------------------------------------------------------------
extern "C" void kernel_launch(void* const* d_in, const int* in_sizes, int n_in,
                              void* d_out, int out_size, void* d_ws, size_t ws_size,
                              hipStream_t stream) {
  (void)in_sizes; (void)n_in; (void)out_size; (void)ws_size;
  const float* x  = (const float*)d_in[0];
  const float* Wq = (const float*)d_in[1];
  const float* bq = (const float*)d_in[2];
  const float* Wk = (const float*)d_in[3];
  const float* bk = (const float*)d_in[4];
  const float* Wv = (const float*)d_in[5];
  const float* bv = (const float*)d_in[6];
  float* out = (float*)d_out;

  char* ws = (char*)d_ws;
  uint16_t* Wp      = (uint16_t*)(ws);                 // 393,216 B
  float*    biascat = (float*)(ws + 393216);           // 1,024 B (768 used)
  uint16_t* Qfrag   = (uint16_t*)(ws + 394240);        // 1,048,576 B
  uint16_t* Kfrag   = (uint16_t*)(ws + 1442816);       // 1,048,576 B
  uint16_t* Vfrag   = (uint16_t*)(ws + 2491392);       // 1,048,576 B
  float*    partial = (float*)(ws + 3539968);          // 5,242,880 B
  float*    lpart   = (float*)(ws + 8782848);          // 81,920 B

  hipLaunchKernelGGL(wconv_kernel, dim3(96), dim3(256), 0, stream,
                     Wq, bq, Wk, bk, Wv, bv, Wp, biascat);
  hipLaunchKernelGGL(proj_kernel, dim3(512), dim3(256), 0, stream,
                     x, Wp, biascat, Qfrag, Kfrag, Vfrag);
  hipLaunchKernelGGL(attn_kernel, dim3(640), dim3(256), 0, stream,
                     Qfrag, Kfrag, Vfrag, partial, lpart);
  hipLaunchKernelGGL(reduce_kernel, dim3(256), dim3(256), 0, stream,
                     partial, lpart, out);
}

// Round 9
// 101.759 us; speedup vs baseline: 1.1233x; 1.0386x over previous
//
#include <hip/hip_runtime.h>
#include <stdint.h>

#define B_  4
#define T_  2048
#define C_  1024
#define D_  64

typedef float  f32x4  __attribute__((ext_vector_type(4)));
typedef float  f32x16 __attribute__((ext_vector_type(16)));
typedef short  s16x8  __attribute__((ext_vector_type(8)));

// softmax scale folded into Q-side weights/bias: 1/sqrt(64) * log2(e)
#define QSCALE 0.18033688011112042f

static __device__ __forceinline__ uint32_t f2bf(float f) {
  uint32_t u = __builtin_bit_cast(uint32_t, f);
  u += 0x7FFFu + ((u >> 16) & 1u);   // round-to-nearest-even
  return u >> 16;
}
static __device__ __forceinline__ uint32_t pack2bf(float a, float b) {
  return f2bf(a) | (f2bf(b) << 16);
}

// ---------------------------------------------------------------------------
// Kernel 1: pack W into MFMA-A-fragment order (verified R3-R7).
// ---------------------------------------------------------------------------
__global__ __launch_bounds__(256) void wconv_kernel(
    const float* __restrict__ Wq, const float* __restrict__ bq,
    const float* __restrict__ Wk, const float* __restrict__ bk,
    const float* __restrict__ Wv, const float* __restrict__ bv,
    uint16_t* __restrict__ Wp, float* __restrict__ biascat) {
  const int g = blockIdx.x * 256 + threadIdx.x;  // 0..24575
  const int s32   = g / 768;
  const int rem   = g - s32 * 768;
  const int ntile = rem >> 6;
  const int l     = rem & 63;
  const int mrow  = l & 15, u = l >> 4;
  const int n     = ntile * 16 + mrow;
  const int mat   = n >> 6, col = n & 63;
  const float* W  = (mat == 0) ? Wq : ((mat == 1) ? Wk : Wv);
  const float  s  = (mat == 0) ? QSCALE : 1.0f;
  const int c0    = s32 * 32 + u * 8;
  float v[8];
#pragma unroll
  for (int j = 0; j < 8; ++j) v[j] = W[(size_t)(c0 + j) * D_ + col] * s;
  uint4 st;
  st.x = pack2bf(v[0], v[1]);
  st.y = pack2bf(v[2], v[3]);
  st.z = pack2bf(v[4], v[5]);
  st.w = pack2bf(v[6], v[7]);
  *reinterpret_cast<uint4*>(Wp + (size_t)g * 8) = st;
  if (g < 192) {
    float bb;
    if (g < 64)       bb = bq[g] * QSCALE;
    else if (g < 128) bb = bk[g - 64];
    else              bb = bv[g - 128];
    biascat[g] = bb;
  }
}

// ---------------------------------------------------------------------------
// Kernel 2: QKV projection with fragment-major epilogue (verified R7).
// ---------------------------------------------------------------------------
__global__ __launch_bounds__(256) void proj_kernel(
    const float* __restrict__ x, const uint16_t* __restrict__ Wp,
    const float* __restrict__ biascat,
    uint16_t* __restrict__ Qfrag, uint16_t* __restrict__ Kfrag,
    uint16_t* __restrict__ Vfrag) {
  __shared__ __align__(16) uint16_t xt[2][16 * 132];    // 8448 B
  __shared__ __align__(16) uint16_t tbuf[4][16 * 28];   // 3584 B
  const int tid  = threadIdx.x;
  const int wave = tid >> 6;
  const int lane = tid & 63;
  const int mrow = lane & 15;
  const int u    = lane >> 4;
  const int m0   = blockIdx.x * 16;
  const int srow = tid >> 4, scol = tid & 15;

  const float* xg = x + (size_t)(m0 + srow) * C_ + scol * 4;

  f32x4 acc[3];
#pragma unroll
  for (int i = 0; i < 3; ++i)
#pragma unroll
    for (int r = 0; r < 4; ++r) acc[i][r] = 0.f;

  float4 xv0 = *reinterpret_cast<const float4*>(xg);
  float4 xv1 = *reinterpret_cast<const float4*>(xg + 64);
  {
    uint2 w0, w1;
    w0.x = pack2bf(xv0.x, xv0.y);  w0.y = pack2bf(xv0.z, xv0.w);
    w1.x = pack2bf(xv1.x, xv1.y);  w1.y = pack2bf(xv1.z, xv1.w);
    *reinterpret_cast<uint2*>(&xt[0][srow * 132 + scol * 4])      = w0;
    *reinterpret_cast<uint2*>(&xt[0][srow * 132 + scol * 4 + 64]) = w1;
  }
  __syncthreads();

  for (int s = 0; s < 8; ++s) {
    const int cur = s & 1;
    if (s < 7) {  // prefetch next slab (overlaps the 12 MFMAs below)
      xv0 = *reinterpret_cast<const float4*>(xg + (s + 1) * 128);
      xv1 = *reinterpret_cast<const float4*>(xg + (s + 1) * 128 + 64);
    }
#pragma unroll
    for (int step = 0; step < 4; ++step) {
      const int s32 = s * 4 + step;
      s16x8 bf = *reinterpret_cast<const s16x8*>(
          &xt[cur][mrow * 132 + step * 32 + u * 8]);
      const uint16_t* wb = Wp + ((size_t)(s32 * 12 + wave * 3) * 64 + lane) * 8;
      s16x8 a0 = *reinterpret_cast<const s16x8*>(wb);
      s16x8 a1 = *reinterpret_cast<const s16x8*>(wb + 64 * 8);
      s16x8 a2 = *reinterpret_cast<const s16x8*>(wb + 128 * 8);
      acc[0] = __builtin_amdgcn_mfma_f32_16x16x32_bf16(a0, bf, acc[0], 0, 0, 0);
      acc[1] = __builtin_amdgcn_mfma_f32_16x16x32_bf16(a1, bf, acc[1], 0, 0, 0);
      acc[2] = __builtin_amdgcn_mfma_f32_16x16x32_bf16(a2, bf, acc[2], 0, 0, 0);
    }
    if (s < 7) {
      uint2 w0, w1;
      w0.x = pack2bf(xv0.x, xv0.y);  w0.y = pack2bf(xv0.z, xv0.w);
      w1.x = pack2bf(xv1.x, xv1.y);  w1.y = pack2bf(xv1.z, xv1.w);
      *reinterpret_cast<uint2*>(&xt[cur ^ 1][srow * 132 + scol * 4])      = w0;
      *reinterpret_cast<uint2*>(&xt[cur ^ 1][srow * 132 + scol * 4 + 64]) = w1;
      __syncthreads();
    }
  }

  const int bb = m0 >> 11;         // batch
  const int mm = m0 & (T_ - 1);    // t offset within batch
#pragma unroll
  for (int nt = 0; nt < 3; ++nt) {
    const int nb = wave * 48 + nt * 16;
    uint16_t vals[4];
#pragma unroll
    for (int r = 0; r < 4; ++r)
      vals[r] = (uint16_t)f2bf(acc[nt][r] + biascat[nb + u * 4 + r]);
    if (nb >= 128) {
      // V -> fragment-major (verified R7)
      const int tg  = mm + mrow;
      const int t   = tg >> 5, rem = tg & 31;
      const int kc  = rem >> 4, hi2 = (rem >> 3) & 1, jj = rem & 7;
      uint16_t* base = Vfrag + ((size_t)(bb * 64 + t)) * 2048;
#pragma unroll
      for (int r = 0; r < 4; ++r) {
        int d = nb - 128 + u * 4 + r;
        int i = (d >> 5) * 2 + kc;
        int l = hi2 * 32 + (d & 31);
        base[i * 512 + l * 8 + jj] = vals[r];
      }
    } else {
      // Q/K: per-wave LDS transpose, then fragment-order stores (R7)
#pragma unroll
      for (int r = 0; r < 4; ++r)
        tbuf[wave][mrow * 28 + u * 4 + r] = vals[r];
      const int row = lane >> 2, qtr = lane & 3;
      uint2 v = *reinterpret_cast<const uint2*>(&tbuf[wave][row * 28 + qtr * 4]);
      const int m  = m0 + row;
      const int e0 = (nb & 63) + qtr * 4;
      const int t  = (m & 2047) >> 5;
      const int c  = e0 >> 4, hi2 = (e0 >> 3) & 1, j0 = e0 & 7;
      uint16_t* dst = (nb < 64) ? Qfrag : Kfrag;
      *reinterpret_cast<uint2*>(
          dst + ((size_t)(bb * 64 + t)) * 2048 + c * 512 +
          (hi2 * 32 + (m & 31)) * 8 + j0) = v;
    }
  }
}

// ---------------------------------------------------------------------------
// Kernel 3: attention + reduce fused. One block per (b,qt): 256 blocks x
// 512 threads (8 waves), waves interleave k-tiles stride-8 (<=8 serial
// steps), LDS merge across 8 waves, normalize in-block, write out directly.
// No partials, no 4th kernel. K-loop body verbatim from R7 (fragment-major
// loads + shfl P-transform). slot(dm,r,hi,ql) = dm*1024 + r*64 + hi*32 + ql.
// ---------------------------------------------------------------------------
__global__ __launch_bounds__(512) void attn_kernel(
    const uint16_t* __restrict__ Qfrag, const uint16_t* __restrict__ Kfrag,
    const uint16_t* __restrict__ Vfrag, float* __restrict__ out) {
  __shared__ float wpart[8 * 2048];   // 65536 B (trans overlays after merge)
  __shared__ float lw[8 * 32];        // 1024 B
  __shared__ float lbuf[32];          // 128 B

  const int tid  = threadIdx.x;       // 0..511
  const int wave = tid >> 6;          // 0..7
  const int lane = tid & 63;
  const int ql   = lane & 31;
  const int hi   = lane >> 5;

  const int blk = blockIdx.x;         // 256 = 64 qt x 4 b
  const int b   = blk & 3;
  const int qt  = 63 - (blk >> 2);    // largest jobs first

  // Q fragments: coalesced 16B/lane (verified R7)
  s16x8 qf[4];
  {
    const uint16_t* qg = Qfrag + ((size_t)(b * 64 + qt)) * 2048 + lane * 8;
#pragma unroll
    for (int c = 0; c < 4; ++c)
      qf[c] = *reinterpret_cast<const s16x8*>(qg + c * 512);
  }

  f32x16 aco[2];
#pragma unroll
  for (int i = 0; i < 2; ++i)
#pragma unroll
    for (int r = 0; r < 16; ++r) aco[i][r] = 0.f;
  float lacc = 0.f;

  auto load_tile = [&](int t, s16x8* kf, s16x8* vf) {
    const uint16_t* kg = Kfrag + ((size_t)(b * 64 + t)) * 2048 + lane * 8;
#pragma unroll
    for (int c = 0; c < 4; ++c)
      kf[c] = *reinterpret_cast<const s16x8*>(kg + c * 512);
    const uint16_t* vg = Vfrag + ((size_t)(b * 64 + t)) * 2048 + lane * 8;
#pragma unroll
    for (int i = 0; i < 4; ++i)   // i = dm*2+kc
      vf[i] = *reinterpret_cast<const s16x8*>(vg + i * 512);
  };

  auto compute = [&](int t, const s16x8* kf, const s16x8* vf) {
    f32x16 sacc;
#pragma unroll
    for (int r = 0; r < 16; ++r) sacc[r] = 0.f;
#pragma unroll
    for (int c = 0; c < 4; ++c)
      sacc = __builtin_amdgcn_mfma_f32_32x32x16_bf16(kf[c], qf[c], sacc, 0, 0, 0);
    if (t == qt) {  // diagonal tile: causal mask
#pragma unroll
      for (int r = 0; r < 16; ++r) {
        const int koff = (r & 3) + 8 * (r >> 2) + 4 * hi;
        sacc[r] = (koff > ql) ? -1e30f : sacc[r];
      }
    }
    float p[16];
#pragma unroll
    for (int r = 0; r < 16; ++r) p[r] = __builtin_amdgcn_exp2f(sacc[r]);
    float s01 = (p[0] + p[1]) + (p[2] + p[3]);
    float s23 = (p[4] + p[5]) + (p[6] + p[7]);
    float s45 = (p[8] + p[9]) + (p[10] + p[11]);
    float s67 = (p[12] + p[13]) + (p[14] + p[15]);
    lacc += (s01 + s23) + (s45 + s67);

    // P -> B-frag via lane-pair exchange (ql <-> ql+32), verified R5-R7
    uint32_t A0 = pack2bf(p[0], p[1]),  A1 = pack2bf(p[2], p[3]);
    uint32_t B0 = pack2bf(p[4], p[5]),  B1 = pack2bf(p[6], p[7]);
    uint32_t C0 = pack2bf(p[8], p[9]),  C1 = pack2bf(p[10], p[11]);
    uint32_t D0 = pack2bf(p[12], p[13]), D1 = pack2bf(p[14], p[15]);
    uint32_t r0 = (uint32_t)__shfl_xor((int)(hi ? A0 : B0), 32, 64);
    uint32_t r1 = (uint32_t)__shfl_xor((int)(hi ? A1 : B1), 32, 64);
    uint32_t r2 = (uint32_t)__shfl_xor((int)(hi ? C0 : D0), 32, 64);
    uint32_t r3 = (uint32_t)__shfl_xor((int)(hi ? C1 : D1), 32, 64);
    union { uint32_t u[4]; s16x8 v; } pf0, pf1;
    pf0.u[0] = hi ? r0 : A0;  pf0.u[1] = hi ? r1 : A1;
    pf0.u[2] = hi ? B0 : r0;  pf0.u[3] = hi ? B1 : r1;
    pf1.u[0] = hi ? r2 : C0;  pf1.u[1] = hi ? r3 : C1;
    pf1.u[2] = hi ? D0 : r2;  pf1.u[3] = hi ? D1 : r3;
    aco[0] = __builtin_amdgcn_mfma_f32_32x32x16_bf16(vf[0], pf0.v, aco[0], 0, 0, 0);
    aco[1] = __builtin_amdgcn_mfma_f32_32x32x16_bf16(vf[2], pf0.v, aco[1], 0, 0, 0);
    aco[0] = __builtin_amdgcn_mfma_f32_32x32x16_bf16(vf[1], pf1.v, aco[0], 0, 0, 0);
    aco[1] = __builtin_amdgcn_mfma_f32_32x32x16_bf16(vf[3], pf1.v, aco[1], 0, 0, 0);
  };

  // register-double-buffered k-loop, stride 8 (<=8 tiles per wave)
  {
    int t = wave;
    if (t <= qt) {
      s16x8 kfA[4], vfA[4], kfB[4], vfB[4];
      load_tile(t, kfA, vfA);
      while (true) {
        int tn = t + 8;
        if (tn <= qt) load_tile(tn, kfB, vfB);
        compute(t, kfA, vfA);
        if (tn > qt) break;
        t = tn; tn = t + 8;
        if (tn <= qt) load_tile(tn, kfA, vfA);
        compute(t, kfB, vfB);
        if (tn > qt) break;
        t = tn;
      }
    }
  }

  lacc += __shfl_xor(lacc, 32, 64);

  // 8-wave LDS merge (extends verified R4-R7 pattern)
#pragma unroll
  for (int dm = 0; dm < 2; ++dm)
#pragma unroll
    for (int r = 0; r < 16; ++r)
      wpart[wave * 2048 + dm * 1024 + r * 64 + hi * 32 + ql] = aco[dm][r];
  if (hi == 0) lw[wave * 32 + ql] = lacc;
  __syncthreads();

  // merge 8 waves in slot space: 512 threads x 4 slots
  const int base = tid * 4;
  float4 s0 = {0.f, 0.f, 0.f, 0.f};
#pragma unroll
  for (int w = 0; w < 8; ++w) {
    float4 a = *reinterpret_cast<const float4*>(wpart + w * 2048 + base);
    s0.x += a.x; s0.y += a.y; s0.z += a.z; s0.w += a.w;
  }
  if (tid < 32) {
    float ls = 0.f;
#pragma unroll
    for (int w = 0; w < 8; ++w) ls += lw[w * 32 + tid];
    lbuf[tid] = 1.0f / ls;
  }
  __syncthreads();  // all wpart reads done before trans overlay

  // slot decode -> trans[d][q] (overlay on wpart)
  float* trans = wpart;
  {
    const int dm = base >> 10, r = (base >> 6) & 15, h2 = (base >> 5) & 1;
    const int ql0 = base & 31;
    const int d = dm * 32 + (r & 3) + 8 * (r >> 2) + 4 * h2;
    float* tr = &trans[d * 33 + ql0];
    tr[0] = s0.x; tr[1] = s0.y; tr[2] = s0.z; tr[3] = s0.w;
  }
  __syncthreads();

  // normalize + write out: 512 threads x 4 elems, [q][d] coalesced
  {
    const int q  = tid >> 4;
    const int dg = (tid & 15) * 4;
    const float rinv = lbuf[q];
    float4 o;
    o.x = trans[(dg + 0) * 33 + q] * rinv;
    o.y = trans[(dg + 1) * 33 + q] * rinv;
    o.z = trans[(dg + 2) * 33 + q] * rinv;
    o.w = trans[(dg + 3) * 33 + q] * rinv;
    *reinterpret_cast<float4*>(
        out + ((size_t)(b * T_ + qt * 32 + q)) * D_ + dg) = o;
  }
}

// ---------------------------------------------------------------------------
extern "C" void kernel_launch(void* const* d_in, const int* in_sizes, int n_in,
                              void* d_out, int out_size, void* d_ws, size_t ws_size,
                              hipStream_t stream) {
  (void)in_sizes; (void)n_in; (void)out_size; (void)ws_size;
  const float* x  = (const float*)d_in[0];
  const float* Wq = (const float*)d_in[1];
  const float* bq = (const float*)d_in[2];
  const float* Wk = (const float*)d_in[3];
  const float* bk = (const float*)d_in[4];
  const float* Wv = (const float*)d_in[5];
  const float* bv = (const float*)d_in[6];
  float* out = (float*)d_out;

  char* ws = (char*)d_ws;
  uint16_t* Wp      = (uint16_t*)(ws);                 // 393,216 B
  float*    biascat = (float*)(ws + 393216);           // 1,024 B (768 used)
  uint16_t* Qfrag   = (uint16_t*)(ws + 394240);        // 1,048,576 B
  uint16_t* Kfrag   = (uint16_t*)(ws + 1442816);       // 1,048,576 B
  uint16_t* Vfrag   = (uint16_t*)(ws + 2491392);       // 1,048,576 B

  hipLaunchKernelGGL(wconv_kernel, dim3(96), dim3(256), 0, stream,
                     Wq, bq, Wk, bk, Wv, bv, Wp, biascat);
  hipLaunchKernelGGL(proj_kernel, dim3(512), dim3(256), 0, stream,
                     x, Wp, biascat, Qfrag, Kfrag, Vfrag);
  hipLaunchKernelGGL(attn_kernel, dim3(256), dim3(512), 0, stream,
                     Qfrag, Kfrag, Vfrag, out);
}